// Round 4
// baseline (322.121 us; speedup 1.0000x reference)
//
#include <hip/hip_runtime.h>

// Problem constants
#define NH   32      // query heads
#define NKV  8       // kv heads
#define LQ   2048    // query length
#define SK   2048    // key length
#define DH   128     // head dim
#define BM   64      // q rows per block (2 q-groups x 32)
#define BN   64      // s columns per iteration (2 s-halves x 32)
#define KSTRIDE 136  // K_lds row stride in shorts (128+8): uniform 8/bank on b128
#define VSTRIDE 72   // Vt_lds row stride in shorts (64+8)
#define PSTRIDE 40   // P strip row stride in shorts (32+8)

typedef __attribute__((ext_vector_type(8)))  short bf8;
typedef __attribute__((ext_vector_type(4)))  float f4;
typedef __attribute__((ext_vector_type(16))) float f16v;

#if __has_builtin(__builtin_amdgcn_exp2f)
#define EXP2F(x) __builtin_amdgcn_exp2f(x)
#else
#define EXP2F(x) exp2f(x)
#endif

// fp32 -> bf16 round-to-nearest-even (finite inputs)
__device__ __forceinline__ unsigned short f2bf(float f) {
    unsigned int u = __builtin_bit_cast(unsigned int, f);
    u = (u + 0x7FFFu + ((u >> 16) & 1u)) >> 16;
    return (unsigned short)u;
}

// ---------------- pre-pass 1: K fp32 -> bf16 (contiguous) ----------------
__global__ __launch_bounds__(256) void convert_k_kernel(
    const float* __restrict__ K, unsigned short* __restrict__ Kb)
{
    size_t base = ((size_t)blockIdx.x * 256 + threadIdx.x) * 8;
    float4 a = *(const float4*)(K + base);
    float4 b = *(const float4*)(K + base + 4);
    bf8 o;
    o[0] = (short)f2bf(a.x); o[1] = (short)f2bf(a.y);
    o[2] = (short)f2bf(a.z); o[3] = (short)f2bf(a.w);
    o[4] = (short)f2bf(b.x); o[5] = (short)f2bf(b.y);
    o[6] = (short)f2bf(b.z); o[7] = (short)f2bf(b.w);
    *(bf8*)(Kb + base) = o;
}

// ---------------- pre-pass 2: V [8][2048][128] fp32 -> VT [8][128][2048] bf16 ----------------
__global__ __launch_bounds__(256) void transpose_v_kernel(
    const float* __restrict__ V, unsigned short* __restrict__ VTb)
{
    __shared__ __align__(16) unsigned short Vl[DH * VSTRIDE];
    const int tid = threadIdx.x;
    const int kv  = blockIdx.x >> 5;          // 32 s-tiles per kv head
    const int s0  = (blockIdx.x & 31) * 64;
    const float* Vh = V + (size_t)kv * SK * DH;

    #pragma unroll
    for (int i = 0; i < 8; ++i) {
        int idx = tid * 4 + i * 1024;
        int s = idx >> 7, d = idx & 127;
        const float4 v4 = *(const float4*)(Vh + (size_t)(s0 + s) * DH + d);
        Vl[(d + 0) * VSTRIDE + s] = f2bf(v4.x);
        Vl[(d + 1) * VSTRIDE + s] = f2bf(v4.y);
        Vl[(d + 2) * VSTRIDE + s] = f2bf(v4.z);
        Vl[(d + 3) * VSTRIDE + s] = f2bf(v4.w);
    }
    __syncthreads();
    unsigned short* out = VTb + (size_t)kv * DH * SK;
    #pragma unroll
    for (int i = 0; i < 4; ++i) {
        int c = tid + i * 256;                // 1024 chunks of 8 shorts
        int d = c >> 3, s8 = (c & 7) * 8;
        *(bf8*)(out + (size_t)d * SK + s0 + s8) = *(const bf8*)(Vl + d * VSTRIDE + s8);
    }
}

// ---------------- main fused attention ----------------
// 4 waves = (qg in {0,1}) x (sh in {0,1}); wave computes S^T tile [32s x 32q]
// for its s-half, softmax, P round-trip (intra-wave), accumulates O^T over its
// s-half; s-halves combined via LDS at the end.
__global__ __launch_bounds__(256, 3) void fattn_kernel(
    const float* __restrict__ Q, const unsigned short* __restrict__ Kb,
    const unsigned short* __restrict__ VTb, const float* __restrict__ M,
    float* __restrict__ O)
{
    // 46080 B total: Klds 17408 + Vlds 18432 + P strips 10240
    __shared__ __align__(16) unsigned short SMEM[23040];
    unsigned short* Klds = SMEM;                 // [64 s][KSTRIDE]
    unsigned short* Vlds = SMEM + 8704;          // [128 d][VSTRIDE]
    unsigned short* Plds = SMEM + 17920;         // 4 waves x [32 q][PSTRIDE]
    float* R  = (float*)SMEM;                    // reduction buf (32768 B, union w/ K+V)
    float* R2 = (float*)(SMEM + 17920);          // l reduction (union w/ P strips)

    const int tid  = threadIdx.x;
    const int wave = tid >> 6;
    const int lane = tid & 63;
    const int l32  = lane & 31;
    const int hh   = lane >> 5;     // half-wave
    const int qg   = wave & 1;      // q-group
    const int sh   = wave >> 1;     // s-half

    const int bx = blockIdx.x;
    const int h  = bx >> 5;         // 32 L-tiles per head
    const int lt = bx & 31;
    const int q0 = lt * BM;
    const int kv = h >> 2;          // N_REP = 4

    const float*          Qh  = Q   + (size_t)h  * LQ * DH;
    const unsigned short* Kh  = Kb  + (size_t)kv * SK * DH;
    const unsigned short* VTh = VTb + (size_t)kv * DH * SK;

    // this lane's q row (n-index of both MFMA stages)
    const int qrow = q0 + qg * 32 + l32;
    const float* Mq = M + (size_t)qrow * SK + sh * 32;

    // ---- preload Q as B-fragments: n=q=l32, k=d = ks*16 + hh*8 + j ----
    bf8 bQ[8];
    #pragma unroll
    for (int ks = 0; ks < 8; ++ks) {
        const float* qp = Qh + (size_t)qrow * DH + ks * 16 + hh * 8;
        float4 a = *(const float4*)(qp);
        float4 b = *(const float4*)(qp + 4);
        bQ[ks][0] = (short)f2bf(a.x); bQ[ks][1] = (short)f2bf(a.y);
        bQ[ks][2] = (short)f2bf(a.z); bQ[ks][3] = (short)f2bf(a.w);
        bQ[ks][4] = (short)f2bf(b.x); bQ[ks][5] = (short)f2bf(b.y);
        bQ[ks][6] = (short)f2bf(b.z); bQ[ks][7] = (short)f2bf(b.w);
    }

    f16v accO[4];     // O^T over this wave's s-half: nt over d (4 x 32); col=q
    #pragma unroll
    for (int nt = 0; nt < 4; ++nt)
        #pragma unroll
        for (int r = 0; r < 16; ++r) accO[nt][r] = 0.f;
    float lpart = 0.f;

    const float scale_log2e = 0.08838834764831845f * 1.4426950408889634f;

    unsigned short* Pw = Plds + wave * 32 * PSTRIDE;

    for (int s0i = 0; s0i < SK; s0i += BN) {
        __syncthreads();
        // ---- stage K tile [64][128] and VT tile [128][64] (bf16, b128) ----
        #pragma unroll
        for (int c = 0; c < 4; ++c) {
            int chunk = tid + c * 256;             // 0..1023
            int sK = chunk >> 4, dK = (chunk & 15) * 8;
            *(bf8*)(Klds + sK * KSTRIDE + dK) =
                *(const bf8*)(Kh + (size_t)(s0i + sK) * DH + dK);
            int dV = chunk >> 3, sV = (chunk & 7) * 8;
            *(bf8*)(Vlds + dV * VSTRIDE + sV) =
                *(const bf8*)(VTh + (size_t)dV * SK + s0i + sV);
        }
        // ---- mask loads (independent of LDS): s = sh*32 + g*8 + hh*4 + r ----
        float4 mv[4];
        #pragma unroll
        for (int g = 0; g < 4; ++g)
            mv[g] = *(const float4*)(Mq + s0i + g * 8 + hh * 4);
        __syncthreads();

        // ---- S^T tile = K Q^T : m = this wave's 32 s, 8 k-steps over D ----
        f16v accS;
        #pragma unroll
        for (int r = 0; r < 16; ++r) accS[r] = 0.f;
        #pragma unroll
        for (int ks = 0; ks < 8; ++ks) {
            bf8 aK = *(const bf8*)(Klds + (sh * 32 + l32) * KSTRIDE + ks * 16 + hh * 8);
            accS = __builtin_amdgcn_mfma_f32_32x32x16_bf16(aK, bQ[ks], accS, 0, 0, 0);
        }

        // ---- softmax (no running max; |z| bounded) + pack P strip [q][32s] ----
        #pragma unroll
        for (int g = 0; g < 4; ++g) {
            ushort4 pk;
            float e0 = EXP2F((accS[g * 4 + 0] + mv[g].x) * scale_log2e);
            float e1 = EXP2F((accS[g * 4 + 1] + mv[g].y) * scale_log2e);
            float e2 = EXP2F((accS[g * 4 + 2] + mv[g].z) * scale_log2e);
            float e3 = EXP2F((accS[g * 4 + 3] + mv[g].w) * scale_log2e);
            lpart += (e0 + e1) + (e2 + e3);
            pk.x = f2bf(e0); pk.y = f2bf(e1); pk.z = f2bf(e2); pk.w = f2bf(e3);
            *(ushort4*)(Pw + l32 * PSTRIDE + g * 8 + hh * 4) = pk;
        }
        // per-wave strip: intra-wave write->read ordering only
        asm volatile("s_waitcnt lgkmcnt(0)" ::: "memory");

        // ---- O^T += V^T P^T over this s-half ----
        bf8 bP[2];
        #pragma unroll
        for (int k2 = 0; k2 < 2; ++k2)
            bP[k2] = *(const bf8*)(Pw + l32 * PSTRIDE + k2 * 16 + hh * 8);
        #pragma unroll
        for (int nt = 0; nt < 4; ++nt) {
            f16v a = accO[nt];
            #pragma unroll
            for (int k2 = 0; k2 < 2; ++k2) {
                bf8 aV = *(const bf8*)(Vlds + (nt * 32 + l32) * VSTRIDE + sh * 32 + k2 * 16 + hh * 8);
                a = __builtin_amdgcn_mfma_f32_32x32x16_bf16(aV, bP[k2], a, 0, 0, 0);
            }
            accO[nt] = a;
        }
    }

    // ---- combine s-halves via LDS, then O = O^T / l ----
    __syncthreads();
    if (sh == 1) {
        float* Rw = R + qg * 4096 + lane * 16;
        #pragma unroll
        for (int nt = 0; nt < 4; ++nt) {
            #pragma unroll
            for (int c = 0; c < 4; ++c) {
                f4 v = {accO[nt][c * 4 + 0], accO[nt][c * 4 + 1],
                        accO[nt][c * 4 + 2], accO[nt][c * 4 + 3]};
                *(f4*)(Rw + nt * 1024 + c * 4) = v;
            }
        }
        R2[qg * 64 + lane] = lpart;
    }
    __syncthreads();
    if (sh == 0) {
        float lsum = lpart + R2[qg * 64 + lane];
        lsum += __shfl_xor(lsum, 32);
        float inv = 1.0f / lsum;
        const float* Rr = R + qg * 4096 + lane * 16;
        float* Op = O + (size_t)h * LQ * DH + (size_t)qrow * DH;
        #pragma unroll
        for (int nt = 0; nt < 4; ++nt) {
            #pragma unroll
            for (int g = 0; g < 4; ++g) {
                f4 p = *(const f4*)(Rr + nt * 1024 + g * 4);
                int d = nt * 32 + g * 8 + hh * 4;
                float4 o;
                o.x = (accO[nt][g * 4 + 0] + p[0]) * inv;
                o.y = (accO[nt][g * 4 + 1] + p[1]) * inv;
                o.z = (accO[nt][g * 4 + 2] + p[2]) * inv;
                o.w = (accO[nt][g * 4 + 3] + p[3]) * inv;
                *(float4*)(Op + d) = o;
            }
        }
    }
}

extern "C" void kernel_launch(void* const* d_in, const int* in_sizes, int n_in,
                              void* d_out, int out_size, void* d_ws, size_t ws_size,
                              hipStream_t stream) {
    const float* Q = (const float*)d_in[0];   // [1,32,2048,128]
    const float* K = (const float*)d_in[1];   // [1,8,2048,128]
    const float* V = (const float*)d_in[2];   // [1,8,2048,128]
    const float* M = (const float*)d_in[3];   // [1,1,2048,2048]
    float* O = (float*)d_out;

    // workspace: Kb bf16 [8*2048*128] then VTb bf16 [8*128*2048]
    unsigned short* Kb  = (unsigned short*)d_ws;
    unsigned short* VTb = Kb + (size_t)NKV * SK * DH;

    convert_k_kernel<<<dim3((NKV * SK * DH) / (256 * 8)), 256, 0, stream>>>(K, Kb);
    transpose_v_kernel<<<dim3(NKV * (SK / 64)), 256, 0, stream>>>(V, VTb);

    dim3 grid(NH * (LQ / BM));                // 32 heads x 32 L-tiles = 1024 blocks
    fattn_kernel<<<grid, 256, 0, stream>>>(Q, Kb, VTb, M, O);
}

// Round 5
// 200.734 us; speedup vs baseline: 1.6047x; 1.6047x over previous
//
#include <hip/hip_runtime.h>

// Problem constants
#define NH   32      // query heads
#define NKV  8       // kv heads
#define LQ   2048    // query length
#define SK   2048    // key length
#define DH   128     // head dim
#define BM   128     // q rows per block (4 waves x 32)
#define BN   64      // s columns per iteration
#define KSTRIDE 136  // K_lds row stride in shorts (128+8): uniform 8/bank on b128
#define VSTRIDE 72   // Vt_lds row stride in shorts (64+8)
#define PSTRIDE 72   // P_lds row stride in shorts (64+8)

typedef __attribute__((ext_vector_type(8)))  short bf8;
typedef __attribute__((ext_vector_type(4)))  float f4;
typedef __attribute__((ext_vector_type(16))) float f16v;

#if __has_builtin(__builtin_amdgcn_exp2f)
#define EXP2F(x) __builtin_amdgcn_exp2f(x)
#else
#define EXP2F(x) exp2f(x)
#endif

// fp32 -> bf16 round-to-nearest-even (finite inputs)
__device__ __forceinline__ unsigned short f2bf(float f) {
    unsigned int u = __builtin_bit_cast(unsigned int, f);
    u = (u + 0x7FFFu + ((u >> 16) & 1u)) >> 16;
    return (unsigned short)u;
}

// ---------------- pre-pass 1: K fp32 -> bf16 (contiguous) ----------------
__global__ __launch_bounds__(256) void convert_k_kernel(
    const float* __restrict__ K, unsigned short* __restrict__ Kb)
{
    size_t base = ((size_t)blockIdx.x * 256 + threadIdx.x) * 8;
    float4 a = *(const float4*)(K + base);
    float4 b = *(const float4*)(K + base + 4);
    bf8 o;
    o[0] = (short)f2bf(a.x); o[1] = (short)f2bf(a.y);
    o[2] = (short)f2bf(a.z); o[3] = (short)f2bf(a.w);
    o[4] = (short)f2bf(b.x); o[5] = (short)f2bf(b.y);
    o[6] = (short)f2bf(b.z); o[7] = (short)f2bf(b.w);
    *(bf8*)(Kb + base) = o;
}

// ---------------- pre-pass 2: V [8][2048][128] fp32 -> VT [8][128][2048] bf16 ----------------
__global__ __launch_bounds__(256) void transpose_v_kernel(
    const float* __restrict__ V, unsigned short* __restrict__ VTb)
{
    __shared__ __align__(16) unsigned short Vl[DH * VSTRIDE];
    const int tid = threadIdx.x;
    const int kv  = blockIdx.x >> 5;          // 32 s-tiles per kv head
    const int s0  = (blockIdx.x & 31) * 64;
    const float* Vh = V + (size_t)kv * SK * DH;

    #pragma unroll
    for (int i = 0; i < 8; ++i) {
        int idx = tid * 4 + i * 1024;
        int s = idx >> 7, d = idx & 127;
        const float4 v4 = *(const float4*)(Vh + (size_t)(s0 + s) * DH + d);
        Vl[(d + 0) * VSTRIDE + s] = f2bf(v4.x);
        Vl[(d + 1) * VSTRIDE + s] = f2bf(v4.y);
        Vl[(d + 2) * VSTRIDE + s] = f2bf(v4.z);
        Vl[(d + 3) * VSTRIDE + s] = f2bf(v4.w);
    }
    __syncthreads();
    unsigned short* out = VTb + (size_t)kv * DH * SK;
    #pragma unroll
    for (int i = 0; i < 4; ++i) {
        int c = tid + i * 256;                // 1024 chunks of 8 shorts
        int d = c >> 3, s8 = (c & 7) * 8;
        *(bf8*)(out + (size_t)d * SK + s0 + s8) = *(const bf8*)(Vl + d * VSTRIDE + s8);
    }
}

// ---------------- main fused attention (R3 structure + register-prefetch pipeline) ----------------
// S^T = K * Q^T   (A = K rows, B = Q^T; D: col=q, row=s)
// O^T = V^T * P^T (A = V^T rows, B = P^T; D: col=q, row=d)
__global__ __launch_bounds__(256, 2) void fattn_kernel(
    const float* __restrict__ Q, const unsigned short* __restrict__ Kb,
    const unsigned short* __restrict__ VTb, const float* __restrict__ M,
    float* __restrict__ O)
{
    __shared__ __align__(16) unsigned short Klds[BN * KSTRIDE];     // [s][d] bf16
    __shared__ __align__(16) unsigned short Vlds[DH * VSTRIDE];     // [d][s] bf16
    __shared__ __align__(16) unsigned short Plds[4 * 32 * PSTRIDE]; // per-wave [q=32][s=64+8]

    const int tid  = threadIdx.x;
    const int wave = tid >> 6;
    const int lane = tid & 63;
    const int l32  = lane & 31;
    const int hh   = lane >> 5;     // half-wave

    const int bx = blockIdx.x;
    const int h  = bx >> 4;         // 16 L-tiles per head
    const int lt = bx & 15;
    const int q0 = lt * BM;
    const int kv = h >> 2;          // N_REP = 4

    const float*          Qh  = Q   + (size_t)h  * LQ * DH;
    const unsigned short* Kh  = Kb  + (size_t)kv * SK * DH;
    const unsigned short* VTh = VTb + (size_t)kv * DH * SK;

    // staging chunk indices (fixed per thread)
    const int sK0 = tid >> 4,        dK0 = (tid & 15) * 8;          // +c*16 rows
    const int dV0 = tid >> 3,        sV0 = (tid & 7) * 8;           // +c*32 rows

    // this lane's q row (n-index of both MFMA stages)
    const int qrow = q0 + wave * 32 + l32;
    const float* Mq = M + (size_t)qrow * SK;

    // ---- preload Q as B-fragments: n=q=l32, k=d = ks*16 + hh*8 + j ----
    bf8 bQ[8];
    #pragma unroll
    for (int ks = 0; ks < 8; ++ks) {
        const float* qp = Qh + (size_t)qrow * DH + ks * 16 + hh * 8;
        float4 a = *(const float4*)(qp);
        float4 b = *(const float4*)(qp + 4);
        bQ[ks][0] = (short)f2bf(a.x); bQ[ks][1] = (short)f2bf(a.y);
        bQ[ks][2] = (short)f2bf(a.z); bQ[ks][3] = (short)f2bf(a.w);
        bQ[ks][4] = (short)f2bf(b.x); bQ[ks][5] = (short)f2bf(b.y);
        bQ[ks][6] = (short)f2bf(b.z); bQ[ks][7] = (short)f2bf(b.w);
    }

    f16v accO[4];     // O^T tiles: nt over d (4 x 32); col=q, row=d
    #pragma unroll
    for (int nt = 0; nt < 4; ++nt)
        #pragma unroll
        for (int r = 0; r < 16; ++r) accO[nt][r] = 0.f;
    float lpart = 0.f;  // per-lane partial softmax denominator for row qrow

    const float scale_log2e = 0.08838834764831845f * 1.4426950408889634f;

    unsigned short* Pw = Plds + wave * 32 * PSTRIDE;

    // ---- prefetch tile 0 into registers ----
    bf8 kf[4], vf[4];
    #pragma unroll
    for (int c = 0; c < 4; ++c) {
        kf[c] = *(const bf8*)(Kh + (size_t)(sK0 + c * 16) * DH + dK0);
        vf[c] = *(const bf8*)(VTh + (size_t)(dV0 + c * 32) * SK + sV0);
    }

    for (int s0i = 0; s0i < SK; s0i += BN) {
        __syncthreads();   // (A) all waves done reading previous tile
        // ---- write prefetched tile to LDS ----
        #pragma unroll
        for (int c = 0; c < 4; ++c) {
            *(bf8*)(Klds + (sK0 + c * 16) * KSTRIDE + dK0) = kf[c];
            *(bf8*)(Vlds + (dV0 + c * 32) * VSTRIDE + sV0) = vf[c];
        }
        __syncthreads();   // (B) staging visible
        // ---- issue global loads for next tile (hidden under compute) ----
        if (s0i + BN < SK) {
            #pragma unroll
            for (int c = 0; c < 4; ++c) {
                kf[c] = *(const bf8*)(Kh + (size_t)(s0i + BN + sK0 + c * 16) * DH + dK0);
                vf[c] = *(const bf8*)(VTh + (size_t)(dV0 + c * 32) * SK + s0i + BN + sV0);
            }
        }
        // ---- mask loads for this iter (L2/L3-resident, hidden under S-phase) ----
        float4 mv[2][4];
        #pragma unroll
        for (int mt = 0; mt < 2; ++mt)
            #pragma unroll
            for (int grp = 0; grp < 4; ++grp)
                mv[mt][grp] = *(const float4*)(Mq + s0i + mt * 32 + grp * 8 + hh * 4);

        // ---- S^T = K Q^T : 2 m-tiles (s), 8 k-steps over D=128 ----
        f16v accS[2];
        #pragma unroll
        for (int mt = 0; mt < 2; ++mt) {
            f16v a;
            #pragma unroll
            for (int r = 0; r < 16; ++r) a[r] = 0.f;
            #pragma unroll
            for (int ks = 0; ks < 8; ++ks) {
                bf8 aK = *(const bf8*)(Klds + (mt * 32 + l32) * KSTRIDE + ks * 16 + hh * 8);
                a = __builtin_amdgcn_mfma_f32_32x32x16_bf16(aK, bQ[ks], a, 0, 0, 0);
            }
            accS[mt] = a;
        }

        // ---- softmax (no running max; |z| bounded) + pack P to per-wave LDS [q][s] ----
        #pragma unroll
        for (int mt = 0; mt < 2; ++mt) {
            #pragma unroll
            for (int grp = 0; grp < 4; ++grp) {
                ushort4 pk;
                float e0 = EXP2F((accS[mt][grp * 4 + 0] + mv[mt][grp].x) * scale_log2e);
                float e1 = EXP2F((accS[mt][grp * 4 + 1] + mv[mt][grp].y) * scale_log2e);
                float e2 = EXP2F((accS[mt][grp * 4 + 2] + mv[mt][grp].z) * scale_log2e);
                float e3 = EXP2F((accS[mt][grp * 4 + 3] + mv[mt][grp].w) * scale_log2e);
                lpart += (e0 + e1) + (e2 + e3);
                pk.x = f2bf(e0); pk.y = f2bf(e1); pk.z = f2bf(e2); pk.w = f2bf(e3);
                *(ushort4*)(Pw + l32 * PSTRIDE + mt * 32 + grp * 8 + hh * 4) = pk;
            }
        }
        // per-wave buffer: intra-wave write->read ordering only
        asm volatile("s_waitcnt lgkmcnt(0)" ::: "memory");

        // ---- O^T += V^T P^T : B-frags of P (4 k-steps), A-frags of V^T (4 d-tiles) ----
        bf8 bP[4];
        #pragma unroll
        for (int ks = 0; ks < 4; ++ks)
            bP[ks] = *(const bf8*)(Pw + l32 * PSTRIDE + ks * 16 + hh * 8);
        #pragma unroll
        for (int nt = 0; nt < 4; ++nt) {
            f16v a = accO[nt];
            #pragma unroll
            for (int ks = 0; ks < 4; ++ks) {
                bf8 aV = *(const bf8*)(Vlds + (nt * 32 + l32) * VSTRIDE + ks * 16 + hh * 8);
                a = __builtin_amdgcn_mfma_f32_32x32x16_bf16(aV, bP[ks], a, 0, 0, 0);
            }
            accO[nt] = a;
        }
    }

    // ---- epilogue: finish l across half-waves, O = O^T / l (float4 stores) ----
    float l = lpart + __shfl_xor(lpart, 32);
    float inv = 1.0f / l;
    float* Op = O + (size_t)h * LQ * DH + (size_t)qrow * DH;
    #pragma unroll
    for (int nt = 0; nt < 4; ++nt) {
        #pragma unroll
        for (int grp = 0; grp < 4; ++grp) {
            int d = nt * 32 + grp * 8 + hh * 4;
            float4 o;
            o.x = accO[nt][grp * 4 + 0] * inv;
            o.y = accO[nt][grp * 4 + 1] * inv;
            o.z = accO[nt][grp * 4 + 2] * inv;
            o.w = accO[nt][grp * 4 + 3] * inv;
            *(float4*)(Op + d) = o;
        }
    }
}

extern "C" void kernel_launch(void* const* d_in, const int* in_sizes, int n_in,
                              void* d_out, int out_size, void* d_ws, size_t ws_size,
                              hipStream_t stream) {
    const float* Q = (const float*)d_in[0];   // [1,32,2048,128]
    const float* K = (const float*)d_in[1];   // [1,8,2048,128]
    const float* V = (const float*)d_in[2];   // [1,8,2048,128]
    const float* M = (const float*)d_in[3];   // [1,1,2048,2048]
    float* O = (float*)d_out;

    // workspace: Kb bf16 [8*2048*128] then VTb bf16 [8*128*2048]
    unsigned short* Kb  = (unsigned short*)d_ws;
    unsigned short* VTb = Kb + (size_t)NKV * SK * DH;

    convert_k_kernel<<<dim3((NKV * SK * DH) / (256 * 8)), 256, 0, stream>>>(K, Kb);
    transpose_v_kernel<<<dim3(NKV * (SK / 64)), 256, 0, stream>>>(V, VTb);

    dim3 grid(NH * (LQ / BM));                // 32 heads x 16 L-tiles = 512 blocks = 2/CU
    fattn_kernel<<<grid, 256, 0, stream>>>(Q, Kb, VTb, M, O);
}